// Round 7
// baseline (152.102 us; speedup 1.0000x reference)
//
#include <hip/hip_runtime.h>

#define BB 4
#define SS 2048
#define DD 64
#define HH 16
#define HDD 4
#define NBH (BB*HH)          // 64 (b,h) pairs
#define NROWS (BB*SS)        // 8192
#define NQ (NBH*SS)          // 131072 query rows
#define QTILES 8             // SS/256 (for combine kernel)
#define LOG2E_HALF 0.7213475204444817f  // log2(e)*0.5 (1/sqrt(HD) folded into K)

// native 2-wide fp32 vector: compiler lowers fma on this to v_pk_fma_f32
// (gfx90a+ packed-FP32), inserting required hazard wait-states itself.
typedef float f32x2 __attribute__((ext_vector_type(2)));

// Branch-free exp2 for s >= 0 (guaranteed: scores are dots of ReLU'd vecs).
// v_exp_f32 measured ~16 cyc/wave64 (1/8 rate) -> replace with full-rate
// packed math: n=trunc(s), f=s-n, deg-4 poly (pk_fma x4), ldexp.
// c4 tuned so p(1)=2 exactly -> continuous at integer seams; max rel err
// ~1.3e-4, far inside the softmax-cancelled output tolerance.
__device__ __forceinline__ f32x2 exp2_nn(f32x2 s) {
    const float tx = truncf(s.x), ty = truncf(s.y);
    const int nx = (int)tx, ny = (int)ty;
    const f32x2 t = {tx, ty};
    const f32x2 f = s - t;
    f32x2 p = {0.011122197f, 0.011122197f};
    p = __builtin_elementwise_fma(p, f, (f32x2){0.0555041087f, 0.0555041087f});
    p = __builtin_elementwise_fma(p, f, (f32x2){0.240226512f, 0.240226512f});
    p = __builtin_elementwise_fma(p, f, (f32x2){0.693147182f, 0.693147182f});
    p = __builtin_elementwise_fma(p, f, (f32x2){1.0f, 1.0f});
    f32x2 e;
    e.x = ldexpf(p.x, nx);   // v_ldexp_f32
    e.y = ldexpf(p.y, ny);
    return e;
}

// ---------------- Kernel 1: QKV projection + ReLU --------------------------
// Q -> [bh][s][4].  K,V -> pair-transposed KV[bh][s/2][16]:
//   {k0x,k1x, k0y,k1y, k0z,k1z, k0w,k1w, v0x,v1x, v0y,v1y, v0z,v1z, v0w,v1w}
// K is prescaled by log2(e)/2.
__global__ __launch_bounds__(256) void qkv_kernel(
    const float* __restrict__ x,
    const float* __restrict__ Wq, const float* __restrict__ bq,
    const float* __restrict__ Wk, const float* __restrict__ bk,
    const float* __restrict__ Wv, const float* __restrict__ bv,
    float* __restrict__ Q, float* __restrict__ KV)
{
    __shared__ float xs[4 * 64];
    const int tid = threadIdx.x;
    const int row0 = blockIdx.x * 4;

    xs[tid] = x[(size_t)row0 * 64 + tid];
    __syncthreads();

    const int r = tid >> 6;
    const int c = tid & 63;
    const int row = row0 + r;
    const int b = row / SS;
    const int s = row % SS;
    const float* xr = &xs[r * 64];

    float aq = bq[c], ak = bk[c], av = bv[c];
    #pragma unroll 16
    for (int k = 0; k < 64; ++k) {
        const float xv = xr[k];
        aq = fmaf(xv, Wq[k * 64 + c], aq);
        ak = fmaf(xv, Wk[k * 64 + c], ak);
        av = fmaf(xv, Wv[k * 64 + c], av);
    }
    aq = fmaxf(aq, 0.0f);
    ak = fmaxf(ak, 0.0f) * LOG2E_HALF;   // fold softmax scale+log2e into K
    av = fmaxf(av, 0.0f);

    const int h = c >> 2, hd = c & 3;
    const size_t bhs = ((size_t)(b * HH + h) * SS + s);
    Q[bhs * 4 + hd] = aq;

    const int p = s >> 1, po = s & 1;
    const size_t pb = ((size_t)(b * HH + h) * (SS / 2) + p) * 16;
    KV[pb + hd * 2 + po] = ak;
    KV[pb + 8 + hd * 2 + po] = av;
}

// ---------------- Kernel 2: attention --------------------------------------
// QROWS query rows per thread share the wave-uniform scalar K/V stream.
// No max-subtraction (relu'd inputs, HD=4: scores bounded, exp2 safe).
template<int KSPLIT, int QROWS, bool DIRECT>
__global__ __launch_bounds__(256) void attn_kernel(
    const float* __restrict__ Qb, const float* __restrict__ KVb,
    const float* __restrict__ x, float* __restrict__ y,
    float* __restrict__ accS, float* __restrict__ sumS)
{
    constexpr int QT = SS / (256 * QROWS);   // q-tiles per bh
    const int tid = threadIdx.x;
    int blk = blockIdx.x;
    const int ks = blk / (NBH * QT);
    blk -= ks * (NBH * QT);
    const int bh = blk / QT;
    const int qt = blk - bh * QT;

    const int PAIRS = SS / 2 / KSPLIT;
    const f32x2* kv = (const f32x2*)(KVb + ((size_t)bh * (SS / 2) + (size_t)ks * PAIRS) * 16);

    f32x2 qx[QROWS], qy[QROWS], qz[QROWS], qw[QROWS];
    #pragma unroll
    for (int r = 0; r < QROWS; ++r) {
        const int qrow = qt * (256 * QROWS) + r * 256 + tid;
        const float4 q = ((const float4*)Qb)[(size_t)bh * SS + qrow];
        qx[r] = {q.x, q.x}; qy[r] = {q.y, q.y};
        qz[r] = {q.z, q.z}; qw[r] = {q.w, q.w};
    }

    f32x2 acx[QROWS], acy[QROWS], acz[QROWS], acw[QROWS], sm[QROWS];
    #pragma unroll
    for (int r = 0; r < QROWS; ++r) {
        acx[r] = {0.f, 0.f}; acy[r] = {0.f, 0.f};
        acz[r] = {0.f, 0.f}; acw[r] = {0.f, 0.f};
        sm[r] = {0.f, 0.f};
    }

    #pragma unroll 4
    for (int j = 0; j < PAIRS; ++j) {
        const f32x2 kx = kv[j * 8 + 0];   // uniform -> scalar loads
        const f32x2 ky = kv[j * 8 + 1];
        const f32x2 kz = kv[j * 8 + 2];
        const f32x2 kw = kv[j * 8 + 3];
        const f32x2 vx = kv[j * 8 + 4];
        const f32x2 vy = kv[j * 8 + 5];
        const f32x2 vz = kv[j * 8 + 6];
        const f32x2 vw = kv[j * 8 + 7];
        #pragma unroll
        for (int r = 0; r < QROWS; ++r) {
            f32x2 s = qx[r] * kx;
            s = __builtin_elementwise_fma(qy[r], ky, s);
            s = __builtin_elementwise_fma(qz[r], kz, s);
            s = __builtin_elementwise_fma(qw[r], kw, s);
            const f32x2 e = exp2_nn(s);
            sm[r] += e;
            acx[r] = __builtin_elementwise_fma(e, vx, acx[r]);
            acy[r] = __builtin_elementwise_fma(e, vy, acy[r]);
            acz[r] = __builtin_elementwise_fma(e, vz, acz[r]);
            acw[r] = __builtin_elementwise_fma(e, vw, acw[r]);
        }
    }

    #pragma unroll
    for (int r = 0; r < QROWS; ++r) {
        const int qrow = qt * (256 * QROWS) + r * 256 + tid;
        const float sum = sm[r].x + sm[r].y;
        float4 acc = {acx[r].x + acx[r].y, acy[r].x + acy[r].y,
                      acz[r].x + acz[r].y, acw[r].x + acw[r].y};
        if (DIRECT) {
            const float inv = 1.0f / sum;
            const int b = bh >> 4, h = bh & 15;
            const size_t o = ((size_t)(b * SS + qrow)) * DD + h * HDD;
            const float4 xr = *(const float4*)(x + o);
            float4 out;
            out.x = fmaf(acc.x, inv, xr.x);
            out.y = fmaf(acc.y, inv, xr.y);
            out.z = fmaf(acc.z, inv, xr.z);
            out.w = fmaf(acc.w, inv, xr.w);
            *(float4*)(y + o) = out;
        } else {
            const size_t qi = (size_t)ks * NQ + (size_t)bh * SS + qrow;
            ((float4*)accS)[qi] = acc;
            sumS[qi] = sum;
        }
    }
}

// ---------------- Kernel 3: combine partials + residual + BN partials ------
template<int KSPLIT>
__global__ __launch_bounds__(256) void combine_bn(
    const float* __restrict__ accS, const float* __restrict__ sumS,
    const float* __restrict__ x, float* __restrict__ y,
    float* __restrict__ part2)
{
    __shared__ float r[4][8];
    const int tid = threadIdx.x;
    const int bh = blockIdx.x >> 3;
    const int qt = blockIdx.x & 7;
    const int qrow = qt * 256 + tid;
    const size_t qi = (size_t)bh * SS + qrow;

    float4 a = ((const float4*)accS)[qi];
    float s = sumS[qi];
    #pragma unroll
    for (int k = 1; k < KSPLIT; ++k) {
        const float4 a2 = ((const float4*)accS)[(size_t)k * NQ + qi];
        a.x += a2.x; a.y += a2.y; a.z += a2.z; a.w += a2.w;
        s += sumS[(size_t)k * NQ + qi];
    }
    const float inv = 1.0f / s;
    const int b = bh >> 4, h = bh & 15;
    const size_t o = ((size_t)(b * SS + qrow)) * DD + h * HDD;
    const float4 xr = *(const float4*)(x + o);
    float4 out;
    out.x = fmaf(a.x, inv, xr.x);
    out.y = fmaf(a.y, inv, xr.y);
    out.z = fmaf(a.z, inv, xr.z);
    out.w = fmaf(a.w, inv, xr.w);
    *(float4*)(y + o) = out;

    float v[8] = {out.x, out.y, out.z, out.w,
                  out.x * out.x, out.y * out.y, out.z * out.z, out.w * out.w};
    #pragma unroll
    for (int i = 0; i < 8; ++i) {
        float t = v[i];
        for (int off = 32; off > 0; off >>= 1) t += __shfl_down(t, off);
        v[i] = t;
    }
    const int wid = tid >> 6;
    if ((tid & 63) == 0) {
        #pragma unroll
        for (int i = 0; i < 8; ++i) r[wid][i] = v[i];
    }
    __syncthreads();
    if (tid < 8) {
        const float t = r[0][tid] + r[1][tid] + r[2][tid] + r[3][tid];
        const int slot = b * 8 + qt;
        const int i = tid & 3;
        const int c = h * 4 + i;
        if (tid < 4) part2[c * 32 + slot] = t;
        else         part2[2048 + c * 32 + slot] = t;
    }
}

// ---------------- Kernel 4: fused BN stats + normalize ---------------------
__global__ __launch_bounds__(256) void bn_norm_fused(
    float* __restrict__ y, const float* __restrict__ part2,
    const float* __restrict__ gamma, const float* __restrict__ beta)
{
    __shared__ float st[128];
    const int tid = threadIdx.x;
    if (tid < 128) {
        const int c = tid & 63;
        const float* p = part2 + (tid >> 6) * 2048 + c * 32;
        float s = 0.f;
        #pragma unroll
        for (int i = 0; i < 32; ++i) s += p[i];
        st[tid] = s;
    }
    __syncthreads();

    const int idx = blockIdx.x * 256 + tid;          // float4 index
    const int c0 = (idx & 15) * 4;
    float4 v = ((const float4*)y)[idx];
    const float n = 1.0f / NROWS;
    const float m0 = st[c0] * n,     m1 = st[c0 + 1] * n;
    const float m2 = st[c0 + 2] * n, m3 = st[c0 + 3] * n;
    const float r0 = rsqrtf(st[64 + c0] * n - m0 * m0 + 1e-5f);
    const float r1 = rsqrtf(st[65 + c0] * n - m1 * m1 + 1e-5f);
    const float r2 = rsqrtf(st[66 + c0] * n - m2 * m2 + 1e-5f);
    const float r3 = rsqrtf(st[67 + c0] * n - m3 * m3 + 1e-5f);
    float4 o;
    o.x = fmaf((v.x - m0) * r0, gamma[c0],     beta[c0]);
    o.y = fmaf((v.y - m1) * r1, gamma[c0 + 1], beta[c0 + 1]);
    o.z = fmaf((v.z - m2) * r2, gamma[c0 + 2], beta[c0 + 2]);
    o.w = fmaf((v.w - m3) * r3, gamma[c0 + 3], beta[c0 + 3]);
    ((float4*)y)[idx] = o;
}

// ---------------- Fallback BN reduce (tiny-workspace path) -----------------
__global__ __launch_bounds__(256) void bn_reduce1(
    const float* __restrict__ y, float* __restrict__ part)
{
    __shared__ float ls[256], ls2[256];
    const int tid = threadIdx.x;
    const int c = tid & 63;
    const int rg = tid >> 6;
    const int row0 = blockIdx.x * 32 + rg * 8;
    float s = 0.0f, s2 = 0.0f;
    #pragma unroll
    for (int i = 0; i < 8; ++i) {
        const float v = y[(size_t)(row0 + i) * 64 + c];
        s += v;
        s2 = fmaf(v, v, s2);
    }
    ls[tid] = s; ls2[tid] = s2;
    __syncthreads();
    if (rg == 0) {
        part[blockIdx.x * 64 + c] = ls[c] + ls[64 + c] + ls[128 + c] + ls[192 + c];
        part[256 * 64 + blockIdx.x * 64 + c] = ls2[c] + ls2[64 + c] + ls2[128 + c] + ls2[192 + c];
    }
}

__global__ __launch_bounds__(256) void bn_reduce2(
    const float* __restrict__ part, float* __restrict__ stats)
{
    __shared__ float ls[256], ls2[256];
    const int tid = threadIdx.x;
    const int c = tid & 63;
    const int pg = tid >> 6;
    float s = 0.0f, s2 = 0.0f;
    for (int i = pg; i < 256; i += 4) {
        s  += part[i * 64 + c];
        s2 += part[256 * 64 + i * 64 + c];
    }
    ls[tid] = s; ls2[tid] = s2;
    __syncthreads();
    if (pg == 0) {
        const float ts  = ls[c]  + ls[64 + c]  + ls[128 + c]  + ls[192 + c];
        const float ts2 = ls2[c] + ls2[64 + c] + ls2[128 + c] + ls2[192 + c];
        const float mean = ts * (1.0f / NROWS);
        const float var  = ts2 * (1.0f / NROWS) - mean * mean;
        stats[c] = mean;
        stats[64 + c] = rsqrtf(var + 1e-5f);
    }
}

__global__ __launch_bounds__(256) void bn_norm(
    float* __restrict__ y, const float* __restrict__ stats,
    const float* __restrict__ gamma, const float* __restrict__ beta)
{
    const int idx = blockIdx.x * 256 + threadIdx.x;
    const int c = idx & 63;
    const float v = y[idx];
    y[idx] = fmaf((v - stats[c]) * stats[64 + c], gamma[c], beta[c]);
}

// ---------------------------------------------------------------------------
extern "C" void kernel_launch(void* const* d_in, const int* in_sizes, int n_in,
                              void* d_out, int out_size, void* d_ws, size_t ws_size,
                              hipStream_t stream)
{
    const float* x     = (const float*)d_in[0];
    const float* Wq    = (const float*)d_in[1];
    const float* bq    = (const float*)d_in[2];
    const float* Wk    = (const float*)d_in[3];
    const float* bk    = (const float*)d_in[4];
    const float* Wv    = (const float*)d_in[5];
    const float* bv    = (const float*)d_in[6];
    const float* gamma = (const float*)d_in[7];
    const float* beta  = (const float*)d_in[8];
    float* out = (float*)d_out;

    float* ws = (float*)d_ws;
    float* Q  = ws;                  // 524288 floats (2 MB)
    float* KV = ws + 524288;         // 1048576 floats (4 MB)

    qkv_kernel<<<NROWS / 4, 256, 0, stream>>>(x, Wq, bq, Wk, bk, Wv, bv, Q, KV);

    const size_t base = 524288 + 1048576;
    auto need = [](int kk) {
        return (size_t)(524288 + 1048576 + (size_t)kk * NQ * 5 + 4096 + 128) * 4;
    };
    constexpr int QR = 2;                      // query rows per thread
    constexpr int QT = SS / (256 * QR);        // 4 q-tiles per bh

    if (ws_size >= need(8)) {
        // 8-way key split: 2048 blocks
        float* accS  = ws + base;
        float* sumS  = accS + (size_t)8 * NQ * 4;
        float* part2 = sumS + (size_t)8 * NQ;
        attn_kernel<8, QR, false><<<8 * NBH * QT, 256, 0, stream>>>(Q, KV, x, out, accS, sumS);
        combine_bn<8><<<NBH * QTILES, 256, 0, stream>>>(accS, sumS, x, out, part2);
        bn_norm_fused<<<NROWS * DD / 1024, 256, 0, stream>>>(out, part2, gamma, beta);
    } else if (ws_size >= need(4)) {
        float* accS  = ws + base;
        float* sumS  = accS + (size_t)4 * NQ * 4;
        float* part2 = sumS + (size_t)4 * NQ;
        attn_kernel<4, QR, false><<<4 * NBH * QT, 256, 0, stream>>>(Q, KV, x, out, accS, sumS);
        combine_bn<4><<<NBH * QTILES, 256, 0, stream>>>(accS, sumS, x, out, part2);
        bn_norm_fused<<<NROWS * DD / 1024, 256, 0, stream>>>(out, part2, gamma, beta);
    } else if (ws_size >= need(2)) {
        float* accS  = ws + base;
        float* sumS  = accS + (size_t)2 * NQ * 4;
        float* part2 = sumS + (size_t)2 * NQ;
        attn_kernel<2, QR, false><<<2 * NBH * QT, 256, 0, stream>>>(Q, KV, x, out, accS, sumS);
        combine_bn<2><<<NBH * QTILES, 256, 0, stream>>>(accS, sumS, x, out, part2);
        bn_norm_fused<<<NROWS * DD / 1024, 256, 0, stream>>>(out, part2, gamma, beta);
    } else {
        float* part  = ws + base;                      // 32768 floats
        float* stats = part + 32768;                   // 128
        attn_kernel<1, QR, true><<<NBH * QT, 256, 0, stream>>>(Q, KV, x, out, nullptr, nullptr);
        bn_reduce1<<<256, 256, 0, stream>>>(out, part);
        bn_reduce2<<<1, 256, 0, stream>>>(part, stats);
        bn_norm<<<NROWS * DD / 256, 256, 0, stream>>>(out, stats, gamma, beta);
    }
}

// Round 8
// 125.561 us; speedup vs baseline: 1.2114x; 1.2114x over previous
//
#include <hip/hip_runtime.h>

#define BB 4
#define SS 2048
#define DD 64
#define HH 16
#define HDD 4
#define NBH (BB*HH)          // 64 (b,h) pairs
#define NROWS (BB*SS)        // 8192
#define NQ (NBH*SS)          // 131072 query rows
#define QTILES 8             // SS/256 (for combine kernel)
#define LOG2E_HALF 0.7213475204444817f  // log2(e)*0.5 (1/sqrt(HD) folded into K)

// native 2-wide fp32 vector: compiler lowers fma on this to v_pk_fma_f32
// (gfx90a+ packed-FP32), inserting required hazard wait-states itself.
typedef float f32x2 __attribute__((ext_vector_type(2)));

// ---------------- Kernel 1: QKV projection + ReLU (packed fp32) ------------
// Each thread owns 2 adjacent output channels -> f32x2 accumulators,
// halving FMA issue count vs scalar. 8 rows per block, 1024 blocks.
// Q -> [bh][s][4].  K,V -> pair-transposed KV[bh][s/2][16]:
//   {k0x,k1x, k0y,k1y, k0z,k1z, k0w,k1w, v0x,v1x, ..., v0w,v1w}
// K is prescaled by log2(e)/2.
__global__ __launch_bounds__(256) void qkv_kernel(
    const float* __restrict__ x,
    const float* __restrict__ Wq, const float* __restrict__ bq,
    const float* __restrict__ Wk, const float* __restrict__ bk,
    const float* __restrict__ Wv, const float* __restrict__ bv,
    float* __restrict__ Q, float* __restrict__ KV)
{
    __shared__ float xs[8 * 64];
    const int tid = threadIdx.x;
    const int row0 = blockIdx.x * 8;

    ((float2*)xs)[tid] = ((const float2*)(x + (size_t)row0 * 64))[tid];
    __syncthreads();

    const int r = tid >> 5;        // 0..7 (row within block)
    const int cp = tid & 31;       // channel pair 0..31
    const int c0 = cp * 2;
    const int row = row0 + r;
    const int b = row >> 11;       // /SS
    const int s = row & (SS - 1);
    const float* xr = &xs[r * 64];

    f32x2 aq = *(const f32x2*)(bq + c0);
    f32x2 ak = *(const f32x2*)(bk + c0);
    f32x2 av = *(const f32x2*)(bv + c0);
    #pragma unroll 8
    for (int k = 0; k < 64; ++k) {
        const float xv = xr[k];
        const f32x2 xv2 = {xv, xv};
        aq = __builtin_elementwise_fma(xv2, *(const f32x2*)(Wq + k * 64 + c0), aq);
        ak = __builtin_elementwise_fma(xv2, *(const f32x2*)(Wk + k * 64 + c0), ak);
        av = __builtin_elementwise_fma(xv2, *(const f32x2*)(Wv + k * 64 + c0), av);
    }
    const f32x2 zero = {0.f, 0.f};
    aq = __builtin_elementwise_max(aq, zero);
    ak = __builtin_elementwise_max(ak, zero);
    av = __builtin_elementwise_max(av, zero);
    ak.x *= LOG2E_HALF; ak.y *= LOG2E_HALF;   // fold softmax scale+log2e into K

    const int h = c0 >> 2, hd = c0 & 3;       // hd in {0,2}
    const size_t bhs = ((size_t)(b * HH + h) * SS + s);
    float2 q2; q2.x = aq.x; q2.y = aq.y;
    *(float2*)(Q + bhs * 4 + hd) = q2;

    const int p = s >> 1, po = s & 1;
    const size_t pb = ((size_t)(b * HH + h) * (SS / 2) + p) * 16;
    KV[pb + hd * 2 + po] = ak.x;
    KV[pb + (hd + 1) * 2 + po] = ak.y;
    KV[pb + 8 + hd * 2 + po] = av.x;
    KV[pb + 8 + (hd + 1) * 2 + po] = av.y;
}

// ---------------- Kernel 2: attention --------------------------------------
// QROWS query rows per thread share the wave-uniform scalar K/V stream.
// No max-subtraction (relu'd inputs, HD=4: scores bounded, exp2 safe).
template<int KSPLIT, int QROWS, bool DIRECT>
__global__ __launch_bounds__(256) void attn_kernel(
    const float* __restrict__ Qb, const float* __restrict__ KVb,
    const float* __restrict__ x, float* __restrict__ y,
    float* __restrict__ accS, float* __restrict__ sumS)
{
    constexpr int QT = SS / (256 * QROWS);   // q-tiles per bh
    const int tid = threadIdx.x;
    int blk = blockIdx.x;
    const int ks = blk / (NBH * QT);
    blk -= ks * (NBH * QT);
    const int bh = blk / QT;
    const int qt = blk - bh * QT;

    const int PAIRS = SS / 2 / KSPLIT;
    const f32x2* kv = (const f32x2*)(KVb + ((size_t)bh * (SS / 2) + (size_t)ks * PAIRS) * 16);

    f32x2 qx[QROWS], qy[QROWS], qz[QROWS], qw[QROWS];
    #pragma unroll
    for (int r = 0; r < QROWS; ++r) {
        const int qrow = qt * (256 * QROWS) + r * 256 + tid;
        const float4 q = ((const float4*)Qb)[(size_t)bh * SS + qrow];
        qx[r] = {q.x, q.x}; qy[r] = {q.y, q.y};
        qz[r] = {q.z, q.z}; qw[r] = {q.w, q.w};
    }

    f32x2 acx[QROWS], acy[QROWS], acz[QROWS], acw[QROWS], sm[QROWS];
    #pragma unroll
    for (int r = 0; r < QROWS; ++r) {
        acx[r] = {0.f, 0.f}; acy[r] = {0.f, 0.f};
        acz[r] = {0.f, 0.f}; acw[r] = {0.f, 0.f};
        sm[r] = {0.f, 0.f};
    }

    #pragma unroll 2
    for (int j = 0; j < PAIRS; ++j) {
        const f32x2 kx = kv[j * 8 + 0];   // uniform -> scalar loads
        const f32x2 ky = kv[j * 8 + 1];
        const f32x2 kz = kv[j * 8 + 2];
        const f32x2 kw = kv[j * 8 + 3];
        const f32x2 vx = kv[j * 8 + 4];
        const f32x2 vy = kv[j * 8 + 5];
        const f32x2 vz = kv[j * 8 + 6];
        const f32x2 vw = kv[j * 8 + 7];
        #pragma unroll
        for (int r = 0; r < QROWS; ++r) {
            f32x2 s = qx[r] * kx;
            s = __builtin_elementwise_fma(qy[r], ky, s);
            s = __builtin_elementwise_fma(qz[r], kz, s);
            s = __builtin_elementwise_fma(qw[r], kw, s);
            f32x2 e;
            e.x = __builtin_amdgcn_exp2f(s.x);
            e.y = __builtin_amdgcn_exp2f(s.y);
            sm[r] += e;
            acx[r] = __builtin_elementwise_fma(e, vx, acx[r]);
            acy[r] = __builtin_elementwise_fma(e, vy, acy[r]);
            acz[r] = __builtin_elementwise_fma(e, vz, acz[r]);
            acw[r] = __builtin_elementwise_fma(e, vw, acw[r]);
        }
    }

    #pragma unroll
    for (int r = 0; r < QROWS; ++r) {
        const int qrow = qt * (256 * QROWS) + r * 256 + tid;
        const float sum = sm[r].x + sm[r].y;
        float4 acc = {acx[r].x + acx[r].y, acy[r].x + acy[r].y,
                      acz[r].x + acz[r].y, acw[r].x + acw[r].y};
        if (DIRECT) {
            const float inv = 1.0f / sum;
            const int b = bh >> 4, h = bh & 15;
            const size_t o = ((size_t)(b * SS + qrow)) * DD + h * HDD;
            const float4 xr = *(const float4*)(x + o);
            float4 out;
            out.x = fmaf(acc.x, inv, xr.x);
            out.y = fmaf(acc.y, inv, xr.y);
            out.z = fmaf(acc.z, inv, xr.z);
            out.w = fmaf(acc.w, inv, xr.w);
            *(float4*)(y + o) = out;
        } else {
            const size_t qi = (size_t)ks * NQ + (size_t)bh * SS + qrow;
            ((float4*)accS)[qi] = acc;
            sumS[qi] = sum;
        }
    }
}

// ---------------- Kernel 3: combine partials + residual + BN partials ------
template<int KSPLIT>
__global__ __launch_bounds__(256) void combine_bn(
    const float* __restrict__ accS, const float* __restrict__ sumS,
    const float* __restrict__ x, float* __restrict__ y,
    float* __restrict__ part2)
{
    __shared__ float r[4][8];
    const int tid = threadIdx.x;
    const int bh = blockIdx.x >> 3;
    const int qt = blockIdx.x & 7;
    const int qrow = qt * 256 + tid;
    const size_t qi = (size_t)bh * SS + qrow;

    float4 a = ((const float4*)accS)[qi];
    float s = sumS[qi];
    #pragma unroll
    for (int k = 1; k < KSPLIT; ++k) {
        const float4 a2 = ((const float4*)accS)[(size_t)k * NQ + qi];
        a.x += a2.x; a.y += a2.y; a.z += a2.z; a.w += a2.w;
        s += sumS[(size_t)k * NQ + qi];
    }
    const float inv = 1.0f / s;
    const int b = bh >> 4, h = bh & 15;
    const size_t o = ((size_t)(b * SS + qrow)) * DD + h * HDD;
    const float4 xr = *(const float4*)(x + o);
    float4 out;
    out.x = fmaf(a.x, inv, xr.x);
    out.y = fmaf(a.y, inv, xr.y);
    out.z = fmaf(a.z, inv, xr.z);
    out.w = fmaf(a.w, inv, xr.w);
    *(float4*)(y + o) = out;

    float v[8] = {out.x, out.y, out.z, out.w,
                  out.x * out.x, out.y * out.y, out.z * out.z, out.w * out.w};
    #pragma unroll
    for (int i = 0; i < 8; ++i) {
        float t = v[i];
        for (int off = 32; off > 0; off >>= 1) t += __shfl_down(t, off);
        v[i] = t;
    }
    const int wid = tid >> 6;
    if ((tid & 63) == 0) {
        #pragma unroll
        for (int i = 0; i < 8; ++i) r[wid][i] = v[i];
    }
    __syncthreads();
    if (tid < 8) {
        const float t = r[0][tid] + r[1][tid] + r[2][tid] + r[3][tid];
        const int slot = b * 8 + qt;
        const int i = tid & 3;
        const int c = h * 4 + i;
        if (tid < 4) part2[c * 32 + slot] = t;
        else         part2[2048 + c * 32 + slot] = t;
    }
}

// ---------------- Kernel 4: fused BN stats + normalize ---------------------
__global__ __launch_bounds__(256) void bn_norm_fused(
    float* __restrict__ y, const float* __restrict__ part2,
    const float* __restrict__ gamma, const float* __restrict__ beta)
{
    __shared__ float st[128];
    const int tid = threadIdx.x;
    if (tid < 128) {
        const int c = tid & 63;
        const float* p = part2 + (tid >> 6) * 2048 + c * 32;
        float s = 0.f;
        #pragma unroll
        for (int i = 0; i < 32; ++i) s += p[i];
        st[tid] = s;
    }
    __syncthreads();

    const int idx = blockIdx.x * 256 + tid;          // float4 index
    const int c0 = (idx & 15) * 4;
    float4 v = ((const float4*)y)[idx];
    const float n = 1.0f / NROWS;
    const float m0 = st[c0] * n,     m1 = st[c0 + 1] * n;
    const float m2 = st[c0 + 2] * n, m3 = st[c0 + 3] * n;
    const float r0 = rsqrtf(st[64 + c0] * n - m0 * m0 + 1e-5f);
    const float r1 = rsqrtf(st[65 + c0] * n - m1 * m1 + 1e-5f);
    const float r2 = rsqrtf(st[66 + c0] * n - m2 * m2 + 1e-5f);
    const float r3 = rsqrtf(st[67 + c0] * n - m3 * m3 + 1e-5f);
    float4 o;
    o.x = fmaf((v.x - m0) * r0, gamma[c0],     beta[c0]);
    o.y = fmaf((v.y - m1) * r1, gamma[c0 + 1], beta[c0 + 1]);
    o.z = fmaf((v.z - m2) * r2, gamma[c0 + 2], beta[c0 + 2]);
    o.w = fmaf((v.w - m3) * r3, gamma[c0 + 3], beta[c0 + 3]);
    ((float4*)y)[idx] = o;
}

// ---------------- Fallback BN reduce (tiny-workspace path) -----------------
__global__ __launch_bounds__(256) void bn_reduce1(
    const float* __restrict__ y, float* __restrict__ part)
{
    __shared__ float ls[256], ls2[256];
    const int tid = threadIdx.x;
    const int c = tid & 63;
    const int rg = tid >> 6;
    const int row0 = blockIdx.x * 32 + rg * 8;
    float s = 0.0f, s2 = 0.0f;
    #pragma unroll
    for (int i = 0; i < 8; ++i) {
        const float v = y[(size_t)(row0 + i) * 64 + c];
        s += v;
        s2 = fmaf(v, v, s2);
    }
    ls[tid] = s; ls2[tid] = s2;
    __syncthreads();
    if (rg == 0) {
        part[blockIdx.x * 64 + c] = ls[c] + ls[64 + c] + ls[128 + c] + ls[192 + c];
        part[256 * 64 + blockIdx.x * 64 + c] = ls2[c] + ls2[64 + c] + ls2[128 + c] + ls2[192 + c];
    }
}

__global__ __launch_bounds__(256) void bn_reduce2(
    const float* __restrict__ part, float* __restrict__ stats)
{
    __shared__ float ls[256], ls2[256];
    const int tid = threadIdx.x;
    const int c = tid & 63;
    const int pg = tid >> 6;
    float s = 0.0f, s2 = 0.0f;
    for (int i = pg; i < 256; i += 4) {
        s  += part[i * 64 + c];
        s2 += part[256 * 64 + i * 64 + c];
    }
    ls[tid] = s; ls2[tid] = s2;
    __syncthreads();
    if (pg == 0) {
        const float ts  = ls[c]  + ls[64 + c]  + ls[128 + c]  + ls[192 + c];
        const float ts2 = ls2[c] + ls2[64 + c] + ls2[128 + c] + ls2[192 + c];
        const float mean = ts * (1.0f / NROWS);
        const float var  = ts2 * (1.0f / NROWS) - mean * mean;
        stats[c] = mean;
        stats[64 + c] = rsqrtf(var + 1e-5f);
    }
}

__global__ __launch_bounds__(256) void bn_norm(
    float* __restrict__ y, const float* __restrict__ stats,
    const float* __restrict__ gamma, const float* __restrict__ beta)
{
    const int idx = blockIdx.x * 256 + threadIdx.x;
    const int c = idx & 63;
    const float v = y[idx];
    y[idx] = fmaf((v - stats[c]) * stats[64 + c], gamma[c], beta[c]);
}

// ---------------------------------------------------------------------------
extern "C" void kernel_launch(void* const* d_in, const int* in_sizes, int n_in,
                              void* d_out, int out_size, void* d_ws, size_t ws_size,
                              hipStream_t stream)
{
    const float* x     = (const float*)d_in[0];
    const float* Wq    = (const float*)d_in[1];
    const float* bq    = (const float*)d_in[2];
    const float* Wk    = (const float*)d_in[3];
    const float* bk    = (const float*)d_in[4];
    const float* Wv    = (const float*)d_in[5];
    const float* bv    = (const float*)d_in[6];
    const float* gamma = (const float*)d_in[7];
    const float* beta  = (const float*)d_in[8];
    float* out = (float*)d_out;

    float* ws = (float*)d_ws;
    float* Q  = ws;                  // 524288 floats (2 MB)
    float* KV = ws + 524288;         // 1048576 floats (4 MB)

    qkv_kernel<<<NROWS / 8, 256, 0, stream>>>(x, Wq, bq, Wk, bk, Wv, bv, Q, KV);

    const size_t base = 524288 + 1048576;
    auto need = [](int kk) {
        return (size_t)(524288 + 1048576 + (size_t)kk * NQ * 5 + 4096 + 128) * 4;
    };
    constexpr int QR = 2;                      // query rows per thread
    constexpr int QT = SS / (256 * QR);        // 4 q-tiles per bh

    if (ws_size >= need(8)) {
        // 8-way key split: 2048 blocks
        float* accS  = ws + base;
        float* sumS  = accS + (size_t)8 * NQ * 4;
        float* part2 = sumS + (size_t)8 * NQ;
        attn_kernel<8, QR, false><<<8 * NBH * QT, 256, 0, stream>>>(Q, KV, x, out, accS, sumS);
        combine_bn<8><<<NBH * QTILES, 256, 0, stream>>>(accS, sumS, x, out, part2);
        bn_norm_fused<<<NROWS * DD / 1024, 256, 0, stream>>>(out, part2, gamma, beta);
    } else if (ws_size >= need(4)) {
        float* accS  = ws + base;
        float* sumS  = accS + (size_t)4 * NQ * 4;
        float* part2 = sumS + (size_t)4 * NQ;
        attn_kernel<4, QR, false><<<4 * NBH * QT, 256, 0, stream>>>(Q, KV, x, out, accS, sumS);
        combine_bn<4><<<NBH * QTILES, 256, 0, stream>>>(accS, sumS, x, out, part2);
        bn_norm_fused<<<NROWS * DD / 1024, 256, 0, stream>>>(out, part2, gamma, beta);
    } else if (ws_size >= need(2)) {
        float* accS  = ws + base;
        float* sumS  = accS + (size_t)2 * NQ * 4;
        float* part2 = sumS + (size_t)2 * NQ;
        attn_kernel<2, QR, false><<<2 * NBH * QT, 256, 0, stream>>>(Q, KV, x, out, accS, sumS);
        combine_bn<2><<<NBH * QTILES, 256, 0, stream>>>(accS, sumS, x, out, part2);
        bn_norm_fused<<<NROWS * DD / 1024, 256, 0, stream>>>(out, part2, gamma, beta);
    } else {
        float* part  = ws + base;                      // 32768 floats
        float* stats = part + 32768;                   // 128
        attn_kernel<1, QR, true><<<NBH * QT, 256, 0, stream>>>(Q, KV, x, out, nullptr, nullptr);
        bn_reduce1<<<256, 256, 0, stream>>>(out, part);
        bn_reduce2<<<1, 256, 0, stream>>>(part, stats);
        bn_norm<<<NROWS * DD / 256, 256, 0, stream>>>(out, stats, gamma, beta);
    }
}